// Round 13
// baseline (84962.592 us; speedup 1.0000x reference)
//
#include <hip/hip_runtime.h>

#define EPSV 1e-5f

#define AT_LD(p)    __hip_atomic_load((p), __ATOMIC_RELAXED, __HIP_MEMORY_SCOPE_AGENT)
#define AT_ST(p, v) __hip_atomic_store((p), (v), __ATOMIC_RELAXED, __HIP_MEMORY_SCOPE_AGENT)

// ---------------- workspace layout (float offsets) ----------------
static constexpr long OFF_SDH   = 0;        // 8*512 ull tagged h data (LLC lane)
static constexpr long OFF_SDR   = 8192;     // 8*512 ull tagged rh data (LLC lane)
static constexpr long OFF_MEAN  = 16896;    // 512
static constexpr long OFF_SCALE = 17408;    // 512
static constexpr long OFF_OFFS  = 17920;    // 512
static constexpr long OFF_U0    = 24576;    // 8*38*512
static constexpr long OFF_U0N   = OFF_U0    + 155648;
static constexpr long OFF_R1    = OFF_U0N   + 155648;
static constexpr long OFF_U1    = OFF_R1    + 147456;
static constexpr long OFF_R2    = OFF_U1    + 147456;
static constexpr long OFF_U2    = OFF_R2    + 131072;
static constexpr long OFF_Y1    = OFF_U2    + 131072;
static constexpr long OFF_V1    = OFF_Y1    + 262144;
static constexpr long OFF_Y2    = OFF_V1    + 262144;
static constexpr long OFF_V2    = OFF_Y2    + 524288;
static constexpr long OFF_Y3    = OFF_V2    + 524288;
static constexpr long OFF_COND0 = OFF_Y3    + 2097152;
static constexpr long OFF_EWI   = OFF_COND0 + 2097152;
static constexpr long OFF_CGX   = OFF_EWI   + 393216;
static constexpr long OFF_HSEQ  = OFF_CGX   + 6291456;

// zero the LLC tagged buffers (stream-ordered before gru_kernel; replay-safe).
__global__ void init_kernel(float* ws) {
    unsigned long long* sDH = (unsigned long long*)(ws + OFF_SDH);
    unsigned long long* sDR = (unsigned long long*)(ws + OFF_SDR);
    int t = blockIdx.x * 256 + threadIdx.x;
    if (t < 4096) { AT_ST(&sDH[t], 0ull); AT_ST(&sDR[t], 0ull); }
}

// generic dilated valid conv1d, Cout = blockDim.x
__global__ void conv1d_kernel(const float* __restrict__ in, const float* __restrict__ w,
                              const float* __restrict__ b, float* __restrict__ out,
                              int T_in, int T_out, int Cin, int K, int rate) {
    extern __shared__ float s_in[];
    int n = blockIdx.x / T_out, t = blockIdx.x % T_out;
    int Cout = blockDim.x;
    for (int idx = threadIdx.x; idx < K * Cin; idx += Cout) {
        int k = idx / Cin, i = idx - k * Cin;
        s_in[idx] = in[((long)(n * T_in + t + k * rate)) * Cin + i];
    }
    __syncthreads();
    int c = threadIdx.x;
    float acc = b[c];
    for (int j = 0; j < K * Cin; ++j)
        acc += s_in[j] * w[(long)j * Cout + c];
    out[((long)(n * T_out + t)) * Cout + c] = acc;
}

// conv_transpose, kernel=1, SAME
__global__ void tconv1d_kernel(const float* __restrict__ in, const float* __restrict__ w,
                               const float* __restrict__ b, float* __restrict__ out,
                               int T_in, int stride, int Cin) {
    extern __shared__ float s_in[];
    int T_out = T_in * stride;
    int n = blockIdx.x / T_out, s = blockIdx.x % T_out;
    int Cout = blockDim.x;
    int c = threadIdx.x;
    if (s % stride) { out[((long)(n * T_out + s)) * Cout + c] = b[c]; return; }
    for (int i = threadIdx.x; i < Cin; i += Cout)
        s_in[i] = in[((long)(n * T_in + s / stride)) * Cin + i];
    __syncthreads();
    float acc = b[c];
    for (int i = 0; i < Cin; ++i) acc += s_in[i] * w[(long)i * Cout + c];
    out[((long)(n * T_out + s)) * Cout + c] = acc;
}

__global__ void bnstats_kernel(const float* __restrict__ x, const float* __restrict__ bns,
                               const float* __restrict__ bno, float* mean, float* scale,
                               float* offs, int count, int C) {
    int c = blockIdx.x, t = threadIdx.x;
    float s = 0.f, s2 = 0.f;
    for (int j = t; j < count; j += 64) { float v = x[(long)j * C + c]; s += v; s2 += v * v; }
    for (int off = 32; off; off >>= 1) { s += __shfl_down(s, off); s2 += __shfl_down(s2, off); }
    if (t == 0) {
        float m = s / count;
        float var = s2 / count - m * m;
        mean[c] = m;
        scale[c] = bns[c] * rsqrtf(var + EPSV);
        offs[c] = bno[c];
    }
}

__global__ void bnapply_kernel(const float* __restrict__ x, float* __restrict__ out,
                               const float* mean, const float* scale, const float* offs,
                               long total) {
    long i = (long)blockIdx.x * 256 + threadIdx.x;
    if (i >= total) return;
    int c = (int)(i & 511);
    float v = (x[i] - mean[c]) * scale[c] + offs[c];
    out[i] = fmaxf(v, 0.f);
}

__global__ void bnapply_add_kernel(const float* __restrict__ r, const float* __restrict__ base,
                                   float* __restrict__ out, const float* mean, const float* scale,
                                   const float* offs, int T_out, int T_base, int shift) {
    long i = (long)blockIdx.x * 256 + threadIdx.x;
    long total = (long)8 * T_out * 512;
    if (i >= total) return;
    int c = (int)(i & 511);
    long row = i >> 9;
    int n = (int)(row / T_out), t = (int)(row % T_out);
    float v = (r[i] - mean[c]) * scale[c] + offs[c];
    v = fmaxf(v, 0.f);
    out[i] = base[(((long)(n * T_base + t + shift)) << 9) + c] + v;
}

// out[rows x 1536] = A[rows x 512] @ W[512 x 1536]
__global__ void __launch_bounds__(256) rowgemm_kernel(const float* __restrict__ A,
                                                      const float* __restrict__ W,
                                                      float* __restrict__ out, int rows) {
    __shared__ float sA[16 * 512];
    long r0 = (long)blockIdx.x * 16;
    int t = threadIdx.x;
    for (int idx = t; idx < 16 * 512; idx += 256) sA[idx] = A[r0 * 512 + idx];
    __syncthreads();
    float acc[16][6];
#pragma unroll
    for (int r = 0; r < 16; ++r)
#pragma unroll
        for (int j = 0; j < 6; ++j) acc[r][j] = 0.f;
    for (int e = 0; e < 512; ++e) {
        float wv[6];
#pragma unroll
        for (int j = 0; j < 6; ++j) wv[j] = W[(long)e * 1536 + t + 256 * j];
#pragma unroll
        for (int r = 0; r < 16; ++r) {
            float a = sA[r * 512 + e];
#pragma unroll
            for (int j = 0; j < 6; ++j) acc[r][j] += a * wv[j];
        }
    }
    for (int r = 0; r < 16; ++r)
#pragma unroll
        for (int j = 0; j < 6; ++j) out[(r0 + r) * 1536 + t + 256 * j] = acc[r][j];
}

// ---------------- persistent GRU ----------------
// 256 wgs x 512 threads: batch n = blockIdx%8, role = blockIdx/8 owns 16 cols.
// Thread (col=t>>5, sub=t&31) owns h-elements {sub+32k}; 48 weights in VGPRs.
// Exchange: PURE-LLC tagged 8B words (epoch<<32|f32), single relaxed agent
// store publish. NEW: BARRIER-FREE REGISTER GATHER — each thread sweeps its 16
// needed words straight into registers (16 independent dwordx2 sc0 sc1 with
// immediate offsets, one waitcnt, re-sweep until all tags current). Coalesced
// (lanes sub=0..31 -> consecutive words). No barriers, no LDS staging; waves
// fully decoupled. tag>ep during gather impossible (producer advances only
// after this wave's red32 -> wave-lockstep induction). Liveness: bounded
// fallback to proven AT_LD spin after 16 failed sweeps.
#define GRU_LDS_BYTES 86016

__device__ __forceinline__ void pub_word(unsigned long long* sp, unsigned ep, float val) {
    unsigned long long w = ((unsigned long long)ep << 32) | (unsigned long long)__float_as_uint(val);
    AT_ST(sp, w);
}

#define G16LD(IDX, OFFS) \
    asm volatile("global_load_dwordx2 %0, %1, off offset:" OFFS " sc0 sc1" \
                 : "=&v"(v[IDX]) : "v"(base) : "memory")

__device__ __forceinline__ void gather16(const unsigned long long* __restrict__ buf,
                                         int sub, unsigned ep, float* out) {
    const unsigned long long* base = buf + sub;
    unsigned long long v[16];
    int tries = 0;
    for (;;) {
        G16LD(0, "0");     G16LD(1, "256");   G16LD(2, "512");   G16LD(3, "768");
        G16LD(4, "1024");  G16LD(5, "1280");  G16LD(6, "1536");  G16LD(7, "1792");
        G16LD(8, "2048");  G16LD(9, "2304");  G16LD(10, "2560"); G16LD(11, "2816");
        G16LD(12, "3072"); G16LD(13, "3328"); G16LD(14, "3584"); G16LD(15, "3840");
        asm volatile("s_waitcnt vmcnt(0)" ::: "memory");
        __builtin_amdgcn_sched_barrier(0);
        bool ok = true;
#pragma unroll
        for (int k = 0; k < 16; ++k) ok = ok && ((unsigned)(v[k] >> 32) >= ep);
        if (ok) break;
        if (++tries > 16) {   // liveness fallback: proven-coherent atomic spin
#pragma unroll
            for (int k = 0; k < 16; ++k) {
                unsigned long long w = AT_LD(base + 32 * k);
                while ((unsigned)(w >> 32) < ep) { __builtin_amdgcn_s_sleep(1); w = AT_LD(base + 32 * k); }
                v[k] = w;
            }
            break;
        }
    }
#pragma unroll
    for (int k = 0; k < 16; ++k) out[k] = __uint_as_float((unsigned)v[k]);
}

__device__ __forceinline__ float red32(float a) {
    a += __shfl_down(a, 16, 32);
    a += __shfl_down(a, 8, 32);
    a += __shfl_down(a, 4, 32);
    a += __shfl_down(a, 2, 32);
    a += __shfl_down(a, 1, 32);
    return a;
}

__global__ void __launch_bounds__(512, 1) gru_kernel(
    const float* __restrict__ wh, const float* __restrict__ gb, const int* __restrict__ x,
    const float* __restrict__ ewi, const float* __restrict__ cgx,
    unsigned long long* __restrict__ sDH, unsigned long long* __restrict__ sDR,
    float* __restrict__ hseq) {
    extern __shared__ float lds_pad[];   // occupancy pad (1 WG/CU); loop uses NO LDS
    (void)lds_pad;

    int wg = blockIdx.x;
    int n = wg & 7;
    int role = wg >> 3;
    int base = role * 16;
    int t = threadIdx.x;
    int col = t >> 5, sub = t & 31;
    int gcol = base + col;
    bool lead = (sub == 0);

    unsigned long long* sDHn = sDH + n * 512;
    unsigned long long* sDRn = sDR + n * 512;

    // ---- per-thread weights into registers (one-time) ----
    float Wz[16], Wr[16], Wa[16];
#pragma unroll
    for (int k = 0; k < 16; ++k) {
        const float* row = wh + (long)(sub + 32 * k) * 1536;
        Wz[k] = row[gcol];
        Wr[k] = row[512 + gcol];
        Wa[k] = row[1024 + gcol];
    }
    float bzv = 0.f, brv = 0.f, bav = 0.f;
    if (lead) { bzv = gb[gcol]; brv = gb[512 + gcol]; bav = gb[1024 + gcol]; }

    const float* cgxn = cgx + (long)n * 512 * 1536;
    float* hseqn = hseq + (long)n * 8192 * 512;
    float h_own = 0.f;                    // h[gcol], publisher-lane register

    // prefetch gate inputs for step 0
    float gz = 0.f, gr = 0.f, ga = 0.f;
    if (lead) {
        int xv = x[n * 8192];
        const float* e_row = ewi + (long)xv * 1536;
        gz = e_row[gcol] + cgxn[gcol] + bzv;
        gr = e_row[512 + gcol] + cgxn[512 + gcol] + brv;
        ga = e_row[1024 + gcol] + cgxn[1024 + gcol] + bav;
    }

    for (int l = 0; l < 8192; ++l) {
        unsigned ep1 = (unsigned)(l + 1);

        // ---- gather h_state(l) into registers (no barrier, no LDS) ----
        float hb[16];
        if (l > 0) {
            gather16(sDHn, sub, (unsigned)l, hb);
        } else {
#pragma unroll
            for (int k = 0; k < 16; ++k) hb[k] = 0.f;
        }

        // ---- r matvec first: publish rh ASAP (cross-WG critical path) ----
        float accr = 0.f;
#pragma unroll
        for (int k = 0; k < 16; ++k) accr += hb[k] * Wr[k];
        accr = red32(accr);
        if (lead) {
            float rr = 1.f / (1.f + __expf(-(gr + accr)));
            pub_word(&sDRn[gcol], ep1, rr * h_own);
        }

        // ---- z matvec: overlaps rh propagation ----
        float accz = 0.f;
#pragma unroll
        for (int k = 0; k < 16; ++k) accz += hb[k] * Wz[k];
        accz = red32(accz);
        float z = 0.f;
        if (lead) z = 1.f / (1.f + __expf(-(gz + accz)));

        // ---- gather rh(l) into registers ----
        float rb[16];
        gather16(sDRn, sub, ep1, rb);

        // ---- a matvec + h update ----
        float acca = 0.f;
#pragma unroll
        for (int k = 0; k < 16; ++k) acca += rb[k] * Wa[k];
        acca = red32(acca);
        if (lead) {
            float pre = ga + acca;
            float axv = fabsf(pre);
            float ex = __expf(-2.f * axv);
            float th = (1.f - ex) / (1.f + ex);
            float a = copysignf(th, pre);
            float hn = (1.f - z) * h_own + z * a;
            h_own = hn;
            if (l < 8191) pub_word(&sDHn[gcol], ep1, hn);
            hseqn[(long)l * 512 + gcol] = hn;   // 16 leads/WG -> contiguous 64B
            // prefetch next step's gate inputs (hides under next gather)
            if (l < 8191) {
                int xv = x[n * 8192 + l + 1];
                const float* e_row = ewi + (long)xv * 1536;
                const float* c_row = cgxn + (long)((l + 1) >> 4) * 1536;
                gz = e_row[gcol] + c_row[gcol] + bzv;
                gr = e_row[512 + gcol] + c_row[512 + gcol] + brv;
                ga = e_row[1024 + gcol] + c_row[1024 + gcol] + bav;
            }
        }
    }
}

// fused head: relu(h@o1+b1)@o2+b2 -> log_softmax; 16 rows per block
__global__ void __launch_bounds__(256) head_kernel(const float* __restrict__ hseq,
                                                   const float* __restrict__ o1w,
                                                   const float* __restrict__ o1b,
                                                   const float* __restrict__ o2w,
                                                   const float* __restrict__ o2b,
                                                   float* __restrict__ out) {
    __shared__ float hs[16 * 512];
    long row0 = (long)blockIdx.x * 16;
    int t = threadIdx.x;
    for (int idx = t; idx < 16 * 512; idx += 256) hs[idx] = hseq[row0 * 512 + idx];
    __syncthreads();

    int c0 = t, c1 = t + 256;
    float acc[16][2];
#pragma unroll
    for (int r = 0; r < 16; ++r) { acc[r][0] = o1b[c0]; acc[r][1] = o1b[c1]; }
    for (int i = 0; i < 512; ++i) {
        float w0 = o1w[(long)i * 512 + c0], w1 = o1w[(long)i * 512 + c1];
#pragma unroll
        for (int r = 0; r < 16; ++r) {
            float h = hs[r * 512 + i];
            acc[r][0] += h * w0;
            acc[r][1] += h * w1;
        }
    }
    __syncthreads();
#pragma unroll
    for (int r = 0; r < 16; ++r) {
        hs[r * 512 + c0] = fmaxf(acc[r][0], 0.f);
        hs[r * 512 + c1] = fmaxf(acc[r][1], 0.f);
    }
    __syncthreads();

    float acc2[16];
#pragma unroll
    for (int r = 0; r < 16; ++r) acc2[r] = o2b[t];
    for (int i = 0; i < 512; ++i) {
        float w = o2w[(long)i * 256 + t];
#pragma unroll
        for (int r = 0; r < 16; ++r) acc2[r] += hs[r * 512 + i] * w;
    }
    __syncthreads();
#pragma unroll
    for (int r = 0; r < 16; ++r) hs[r * 256 + t] = acc2[r];
    __syncthreads();

    int wave = t >> 6, lane = t & 63;
    for (int rr = 0; rr < 4; ++rr) {
        int r = wave * 4 + rr;
        float v0 = hs[r * 256 + lane];
        float v1 = hs[r * 256 + 64 + lane];
        float v2 = hs[r * 256 + 128 + lane];
        float v3 = hs[r * 256 + 192 + lane];
        float m = fmaxf(fmaxf(v0, v1), fmaxf(v2, v3));
        for (int off = 32; off; off >>= 1) m = fmaxf(m, __shfl_xor(m, off));
        float s = __expf(v0 - m) + __expf(v1 - m) + __expf(v2 - m) + __expf(v3 - m);
        for (int off = 32; off; off >>= 1) s += __shfl_xor(s, off);
        float ls = m + logf(s);
        long ob = (row0 + r) * 256;
        out[ob + lane] = v0 - ls;
        out[ob + 64 + lane] = v1 - ls;
        out[ob + 128 + lane] = v2 - ls;
        out[ob + 192 + lane] = v3 - ls;
    }
}

extern "C" void kernel_launch(void* const* d_in, const int* in_sizes, int n_in,
                              void* d_out, int out_size, void* d_ws, size_t ws_size,
                              hipStream_t stream) {
    const int* x = (const int*)d_in[0];
    const float* mel = (const float*)d_in[1];
    const float* embed_w = (const float*)d_in[2];
    const float* conv_in_w = (const float*)d_in[3];
    const float* conv_in_b = (const float*)d_in[4];
    const float* conv_d1_w = (const float*)d_in[5];
    const float* conv_d1_b = (const float*)d_in[6];
    const float* conv_d2_w = (const float*)d_in[7];
    const float* conv_d2_b = (const float*)d_in[8];
    const float* up1_w = (const float*)d_in[9];
    const float* up1_b = (const float*)d_in[10];
    const float* up2_w = (const float*)d_in[11];
    const float* up2_b = (const float*)d_in[12];
    const float* up3_w = (const float*)d_in[13];
    const float* up3_b = (const float*)d_in[14];
    const float* bn_in_s = (const float*)d_in[15];
    const float* bn_in_o = (const float*)d_in[16];
    const float* bn_d1_s = (const float*)d_in[17];
    const float* bn_d1_o = (const float*)d_in[18];
    const float* bn_d2_s = (const float*)d_in[19];
    const float* bn_d2_o = (const float*)d_in[20];
    const float* bn_u1_s = (const float*)d_in[21];
    const float* bn_u1_o = (const float*)d_in[22];
    const float* bn_u2_s = (const float*)d_in[23];
    const float* bn_u2_o = (const float*)d_in[24];
    const float* bn_u3_s = (const float*)d_in[25];
    const float* bn_u3_o = (const float*)d_in[26];
    const float* gru_wi = (const float*)d_in[27];
    const float* gru_wh = (const float*)d_in[28];
    const float* gru_b = (const float*)d_in[29];
    const float* o1_w = (const float*)d_in[30];
    const float* o1_b = (const float*)d_in[31];
    const float* o2_w = (const float*)d_in[32];
    const float* o2_b = (const float*)d_in[33];

    float* ws = (float*)d_ws;
    float* out = (float*)d_out;

    unsigned long long* sDH = (unsigned long long*)(ws + OFF_SDH);
    unsigned long long* sDR = (unsigned long long*)(ws + OFF_SDR);
    float* mean = ws + OFF_MEAN;
    float* scale = ws + OFF_SCALE;
    float* offs = ws + OFF_OFFS;
    float* u0 = ws + OFF_U0;
    float* u0n = ws + OFF_U0N;
    float* r1 = ws + OFF_R1;
    float* u1 = ws + OFF_U1;
    float* r2 = ws + OFF_R2;
    float* u2 = ws + OFF_U2;
    float* y1 = ws + OFF_Y1;
    float* v1 = ws + OFF_V1;
    float* y2 = ws + OFF_Y2;
    float* v2 = ws + OFF_V2;
    float* y3 = ws + OFF_Y3;
    float* cond0 = ws + OFF_COND0;
    float* ewi = ws + OFF_EWI;
    float* cgx = ws + OFF_CGX;
    float* hseq = ws + OFF_HSEQ;

    init_kernel<<<16, 256, 0, stream>>>(ws);

    // conv_in (K3, rate1) + BN + relu
    conv1d_kernel<<<8 * 38, 512, 240 * 4, stream>>>(mel, conv_in_w, conv_in_b, u0, 40, 38, 80, 3, 1);
    bnstats_kernel<<<512, 64, 0, stream>>>(u0, bn_in_s, bn_in_o, mean, scale, offs, 304, 512);
    bnapply_kernel<<<155648 / 256, 256, 0, stream>>>(u0, u0n, mean, scale, offs, 155648);
    // dilated resblock 1
    conv1d_kernel<<<8 * 36, 512, 1024 * 4, stream>>>(u0n, conv_d1_w, conv_d1_b, r1, 38, 36, 512, 2, 2);
    bnstats_kernel<<<512, 64, 0, stream>>>(r1, bn_d1_s, bn_d1_o, mean, scale, offs, 288, 512);
    bnapply_add_kernel<<<147456 / 256, 256, 0, stream>>>(r1, u0n, u1, mean, scale, offs, 36, 38, 1);
    // dilated resblock 2
    conv1d_kernel<<<8 * 32, 512, 1024 * 4, stream>>>(u1, conv_d2_w, conv_d2_b, r2, 36, 32, 512, 2, 4);
    bnstats_kernel<<<512, 64, 0, stream>>>(r2, bn_d2_s, bn_d2_o, mean, scale, offs, 256, 512);
    bnapply_add_kernel<<<131072 / 256, 256, 0, stream>>>(r2, u1, u2, mean, scale, offs, 32, 36, 2);
    // upsample x2, x2, x4
    tconv1d_kernel<<<8 * 64, 512, 2048, stream>>>(u2, up1_w, up1_b, y1, 32, 2, 512);
    bnstats_kernel<<<512, 64, 0, stream>>>(y1, bn_u1_s, bn_u1_o, mean, scale, offs, 512, 512);
    bnapply_kernel<<<262144 / 256, 256, 0, stream>>>(y1, v1, mean, scale, offs, 262144);
    tconv1d_kernel<<<8 * 128, 512, 2048, stream>>>(v1, up2_w, up2_b, y2, 64, 2, 512);
    bnstats_kernel<<<512, 64, 0, stream>>>(y2, bn_u2_s, bn_u2_o, mean, scale, offs, 1024, 512);
    bnapply_kernel<<<524288 / 256, 256, 0, stream>>>(y2, v2, mean, scale, offs, 524288);
    tconv1d_kernel<<<8 * 512, 512, 2048, stream>>>(v2, up3_w, up3_b, y3, 128, 4, 512);
    bnstats_kernel<<<512, 64, 0, stream>>>(y3, bn_u3_s, bn_u3_o, mean, scale, offs, 4096, 512);
    bnapply_kernel<<<2097152 / 256, 256, 0, stream>>>(y3, cond0, mean, scale, offs, 2097152);

    // collapsed gx: ewi = embed@wi (256x1536), cgx = cond0@wi (4096x1536)
    rowgemm_kernel<<<16, 256, 0, stream>>>(embed_w, gru_wi, ewi, 256);
    rowgemm_kernel<<<256, 256, 0, stream>>>(cond0, gru_wi, cgx, 4096);

    // persistent GRU: 256 wgs x 512 threads; 84KB dynamic pad pins 1 WG/CU
    hipFuncSetAttribute(reinterpret_cast<const void*>(gru_kernel),
                        hipFuncAttributeMaxDynamicSharedMemorySize,
                        GRU_LDS_BYTES);
    gru_kernel<<<256, 512, GRU_LDS_BYTES, stream>>>(
        gru_wh, gru_b, x, ewi, cgx, sDH, sDR, hseq);

    // fused output head + log_softmax
    head_kernel<<<4096, 256, 0, stream>>>(hseq, o1_w, o1_b, o2_w, o2_b, out);
}

// Round 14
// 21124.176 us; speedup vs baseline: 4.0221x; 4.0221x over previous
//
#include <hip/hip_runtime.h>

#define EPSV 1e-5f

#define AT_LD(p)    __hip_atomic_load((p), __ATOMIC_RELAXED, __HIP_MEMORY_SCOPE_AGENT)
#define AT_ST(p, v) __hip_atomic_store((p), (v), __ATOMIC_RELAXED, __HIP_MEMORY_SCOPE_AGENT)

// ---------------- workspace layout (float offsets) ----------------
static constexpr long OFF_SDH   = 0;        // 8*512 ull tagged h data (LLC lane)
static constexpr long OFF_SDR   = 8192;     // 8*512 ull tagged rh data (LLC lane)
static constexpr long OFF_MEAN  = 16896;    // 512
static constexpr long OFF_SCALE = 17408;    // 512
static constexpr long OFF_OFFS  = 17920;    // 512
static constexpr long OFF_U0    = 24576;    // 8*38*512
static constexpr long OFF_U0N   = OFF_U0    + 155648;
static constexpr long OFF_R1    = OFF_U0N   + 155648;
static constexpr long OFF_U1    = OFF_R1    + 147456;
static constexpr long OFF_R2    = OFF_U1    + 147456;
static constexpr long OFF_U2    = OFF_R2    + 131072;
static constexpr long OFF_Y1    = OFF_U2    + 131072;
static constexpr long OFF_V1    = OFF_Y1    + 262144;
static constexpr long OFF_Y2    = OFF_V1    + 262144;
static constexpr long OFF_V2    = OFF_Y2    + 524288;
static constexpr long OFF_Y3    = OFF_V2    + 524288;
static constexpr long OFF_COND0 = OFF_Y3    + 2097152;
static constexpr long OFF_EWI   = OFF_COND0 + 2097152;
static constexpr long OFF_CGX   = OFF_EWI   + 393216;
static constexpr long OFF_HSEQ  = OFF_CGX   + 6291456;

// zero the LLC tagged buffers (stream-ordered before gru_kernel; replay-safe).
__global__ void init_kernel(float* ws) {
    unsigned long long* sDH = (unsigned long long*)(ws + OFF_SDH);
    unsigned long long* sDR = (unsigned long long*)(ws + OFF_SDR);
    int t = blockIdx.x * 256 + threadIdx.x;
    if (t < 4096) { AT_ST(&sDH[t], 0ull); AT_ST(&sDR[t], 0ull); }
}

// generic dilated valid conv1d, Cout = blockDim.x
__global__ void conv1d_kernel(const float* __restrict__ in, const float* __restrict__ w,
                              const float* __restrict__ b, float* __restrict__ out,
                              int T_in, int T_out, int Cin, int K, int rate) {
    extern __shared__ float s_in[];
    int n = blockIdx.x / T_out, t = blockIdx.x % T_out;
    int Cout = blockDim.x;
    for (int idx = threadIdx.x; idx < K * Cin; idx += Cout) {
        int k = idx / Cin, i = idx - k * Cin;
        s_in[idx] = in[((long)(n * T_in + t + k * rate)) * Cin + i];
    }
    __syncthreads();
    int c = threadIdx.x;
    float acc = b[c];
    for (int j = 0; j < K * Cin; ++j)
        acc += s_in[j] * w[(long)j * Cout + c];
    out[((long)(n * T_out + t)) * Cout + c] = acc;
}

// conv_transpose, kernel=1, SAME
__global__ void tconv1d_kernel(const float* __restrict__ in, const float* __restrict__ w,
                               const float* __restrict__ b, float* __restrict__ out,
                               int T_in, int stride, int Cin) {
    extern __shared__ float s_in[];
    int T_out = T_in * stride;
    int n = blockIdx.x / T_out, s = blockIdx.x % T_out;
    int Cout = blockDim.x;
    int c = threadIdx.x;
    if (s % stride) { out[((long)(n * T_out + s)) * Cout + c] = b[c]; return; }
    for (int i = threadIdx.x; i < Cin; i += Cout)
        s_in[i] = in[((long)(n * T_in + s / stride)) * Cin + i];
    __syncthreads();
    float acc = b[c];
    for (int i = 0; i < Cin; ++i) acc += s_in[i] * w[(long)i * Cout + c];
    out[((long)(n * T_out + s)) * Cout + c] = acc;
}

__global__ void bnstats_kernel(const float* __restrict__ x, const float* __restrict__ bns,
                               const float* __restrict__ bno, float* mean, float* scale,
                               float* offs, int count, int C) {
    int c = blockIdx.x, t = threadIdx.x;
    float s = 0.f, s2 = 0.f;
    for (int j = t; j < count; j += 64) { float v = x[(long)j * C + c]; s += v; s2 += v * v; }
    for (int off = 32; off; off >>= 1) { s += __shfl_down(s, off); s2 += __shfl_down(s2, off); }
    if (t == 0) {
        float m = s / count;
        float var = s2 / count - m * m;
        mean[c] = m;
        scale[c] = bns[c] * rsqrtf(var + EPSV);
        offs[c] = bno[c];
    }
}

__global__ void bnapply_kernel(const float* __restrict__ x, float* __restrict__ out,
                               const float* mean, const float* scale, const float* offs,
                               long total) {
    long i = (long)blockIdx.x * 256 + threadIdx.x;
    if (i >= total) return;
    int c = (int)(i & 511);
    float v = (x[i] - mean[c]) * scale[c] + offs[c];
    out[i] = fmaxf(v, 0.f);
}

__global__ void bnapply_add_kernel(const float* __restrict__ r, const float* __restrict__ base,
                                   float* __restrict__ out, const float* mean, const float* scale,
                                   const float* offs, int T_out, int T_base, int shift) {
    long i = (long)blockIdx.x * 256 + threadIdx.x;
    long total = (long)8 * T_out * 512;
    if (i >= total) return;
    int c = (int)(i & 511);
    long row = i >> 9;
    int n = (int)(row / T_out), t = (int)(row % T_out);
    float v = (r[i] - mean[c]) * scale[c] + offs[c];
    v = fmaxf(v, 0.f);
    out[i] = base[(((long)(n * T_base + t + shift)) << 9) + c] + v;
}

// out[rows x 1536] = A[rows x 512] @ W[512 x 1536]
__global__ void __launch_bounds__(256) rowgemm_kernel(const float* __restrict__ A,
                                                      const float* __restrict__ W,
                                                      float* __restrict__ out, int rows) {
    __shared__ float sA[16 * 512];
    long r0 = (long)blockIdx.x * 16;
    int t = threadIdx.x;
    for (int idx = t; idx < 16 * 512; idx += 256) sA[idx] = A[r0 * 512 + idx];
    __syncthreads();
    float acc[16][6];
#pragma unroll
    for (int r = 0; r < 16; ++r)
#pragma unroll
        for (int j = 0; j < 6; ++j) acc[r][j] = 0.f;
    for (int e = 0; e < 512; ++e) {
        float wv[6];
#pragma unroll
        for (int j = 0; j < 6; ++j) wv[j] = W[(long)e * 1536 + t + 256 * j];
#pragma unroll
        for (int r = 0; r < 16; ++r) {
            float a = sA[r * 512 + e];
#pragma unroll
            for (int j = 0; j < 6; ++j) acc[r][j] += a * wv[j];
        }
    }
    for (int r = 0; r < 16; ++r)
#pragma unroll
        for (int j = 0; j < 6; ++j) out[(r0 + r) * 1536 + t + 256 * j] = acc[r][j];
}

// ---------------- persistent GRU ----------------
// 256 wgs x 512 threads: batch n = blockIdx%8, role = blockIdx/8 owns 16 cols.
// Thread (col=t>>5, sub=t&31) owns h-elements {sub+32k}; 48 weights in VGPRs.
// Exchange (R12-proven): PURE-LLC tagged 8B words (epoch<<32|f32), single
// relaxed agent-store publish, per-thread spin on own word.
// R14: scheduler hygiene — spin YIELDS (s_sleep(1) on miss, prio 0) while
// compute+publish segments run at prio 1. Waves split naturally into
// {compute wave on the cross-WG critical path} vs {spinning waves}; the
// scheduler must favor the former (T5 mechanism, real role diversity here).
#define GRU_LDS_BYTES 86016

__device__ __forceinline__ void pub_word(unsigned long long* sp, unsigned ep, float val) {
    unsigned long long w = ((unsigned long long)ep << 32) | (unsigned long long)__float_as_uint(val);
    AT_ST(sp, w);
}

__device__ __forceinline__ float wait_word(const unsigned long long* sp, unsigned ep) {
    unsigned long long v = AT_LD(sp);
    while ((unsigned)(v >> 32) < ep) {
        __builtin_amdgcn_s_sleep(1);      // yield issue slots to compute waves
        v = AT_LD(sp);
    }
    return __uint_as_float((unsigned)(v & 0xFFFFFFFFull));
}

__device__ __forceinline__ float red32(float a) {
    a += __shfl_down(a, 16, 32);
    a += __shfl_down(a, 8, 32);
    a += __shfl_down(a, 4, 32);
    a += __shfl_down(a, 2, 32);
    a += __shfl_down(a, 1, 32);
    return a;
}

__global__ void __launch_bounds__(512, 1) gru_kernel(
    const float* __restrict__ wh, const float* __restrict__ gb, const int* __restrict__ x,
    const float* __restrict__ ewi, const float* __restrict__ cgx,
    unsigned long long* __restrict__ sDH, unsigned long long* __restrict__ sDR,
    float* __restrict__ hseq) {
    __shared__ float h_l[512];
    __shared__ float rh_l[512];
    extern __shared__ float lds_pad[];   // occupancy pad (1 WG/CU)
    (void)lds_pad;

    int wg = blockIdx.x;
    int n = wg & 7;
    int role = wg >> 3;
    int base = role * 16;
    int t = threadIdx.x;
    int col = t >> 5, sub = t & 31;
    int gcol = base + col;
    bool lead = (sub == 0);
    bool own = ((t >> 4) == role);       // this thread's exchange word is own-WG

    unsigned long long* sDHn = sDH + n * 512;
    unsigned long long* sDRn = sDR + n * 512;

    // ---- per-thread weights into registers (one-time) ----
    float Wz[16], Wr[16], Wa[16];
#pragma unroll
    for (int k = 0; k < 16; ++k) {
        const float* row = wh + (long)(sub + 32 * k) * 1536;
        Wz[k] = row[gcol];
        Wr[k] = row[512 + gcol];
        Wa[k] = row[1024 + gcol];
    }
    float bzv = 0.f, brv = 0.f, bav = 0.f;
    if (lead) { bzv = gb[gcol]; brv = gb[512 + gcol]; bav = gb[1024 + gcol]; }

    h_l[t] = 0.f;
    __syncthreads();

    const float* cgxn = cgx + (long)n * 512 * 1536;
    float* hseqn = hseq + (long)n * 8192 * 512;
    float h_own = 0.f;                    // h[gcol], publisher-lane register

    // prefetch gate inputs for step 0
    float gz = 0.f, gr = 0.f, ga = 0.f;
    if (lead) {
        int xv = x[n * 8192];
        const float* e_row = ewi + (long)xv * 1536;
        gz = e_row[gcol] + cgxn[gcol] + bzv;
        gr = e_row[512 + gcol] + cgxn[512 + gcol] + brv;
        ga = e_row[1024 + gcol] + cgxn[1024 + gcol] + bav;
    }

    for (int l = 0; l < 8192; ++l) {
        unsigned ep1 = (unsigned)(l + 1);

        // ---- collect h_state(l): spin at prio 0, yielding ----
        if (l > 0 && !own) h_l[t] = wait_word(&sDHn[t], (unsigned)l);
        __syncthreads();   // B1

        // ---- critical compute: elevated priority ----
        __builtin_amdgcn_s_setprio(1);
        float accr = 0.f;
#pragma unroll
        for (int k = 0; k < 16; ++k) accr += h_l[sub + 32 * k] * Wr[k];
        accr = red32(accr);
        if (lead) {
            float rr = 1.f / (1.f + __expf(-(gr + accr)));
            float rhv = rr * h_own;
            pub_word(&sDRn[gcol], ep1, rhv);
            rh_l[gcol] = rhv;              // own cols local (no self-poll)
        }
        // z matvec: overlaps rh propagation
        float accz = 0.f;
#pragma unroll
        for (int k = 0; k < 16; ++k) accz += h_l[sub + 32 * k] * Wz[k];
        accz = red32(accz);
        float z = 0.f;
        if (lead) z = 1.f / (1.f + __expf(-(gz + accz)));
        __builtin_amdgcn_s_setprio(0);

        // ---- collect rh(l): spin at prio 0, yielding ----
        if (!own) rh_l[t] = wait_word(&sDRn[t], ep1);
        __syncthreads();   // B2

        // ---- critical compute: elevated priority ----
        __builtin_amdgcn_s_setprio(1);
        float acca = 0.f;
#pragma unroll
        for (int k = 0; k < 16; ++k) acca += rh_l[sub + 32 * k] * Wa[k];
        acca = red32(acca);
        if (lead) {
            float pre = ga + acca;
            float axv = fabsf(pre);
            float ex = __expf(-2.f * axv);
            float th = (1.f - ex) / (1.f + ex);
            float a = copysignf(th, pre);
            float hn = (1.f - z) * h_own + z * a;
            h_own = hn;
            if (l < 8191) pub_word(&sDHn[gcol], ep1, hn);
            h_l[gcol] = hn;                // own cols local for next step
            hseqn[(long)l * 512 + gcol] = hn;   // balanced 64B contiguous per WG
            // prefetch next step's gate inputs (hides under next h-wait)
            if (l < 8191) {
                int xv = x[n * 8192 + l + 1];
                const float* e_row = ewi + (long)xv * 1536;
                const float* c_row = cgxn + (long)((l + 1) >> 4) * 1536;
                gz = e_row[gcol] + c_row[gcol] + bzv;
                gr = e_row[512 + gcol] + c_row[512 + gcol] + brv;
                ga = e_row[1024 + gcol] + c_row[1024 + gcol] + bav;
            }
        }
        __builtin_amdgcn_s_setprio(0);
    }
}

// fused head: relu(h@o1+b1)@o2+b2 -> log_softmax; 16 rows per block
__global__ void __launch_bounds__(256) head_kernel(const float* __restrict__ hseq,
                                                   const float* __restrict__ o1w,
                                                   const float* __restrict__ o1b,
                                                   const float* __restrict__ o2w,
                                                   const float* __restrict__ o2b,
                                                   float* __restrict__ out) {
    __shared__ float hs[16 * 512];
    long row0 = (long)blockIdx.x * 16;
    int t = threadIdx.x;
    for (int idx = t; idx < 16 * 512; idx += 256) hs[idx] = hseq[row0 * 512 + idx];
    __syncthreads();

    int c0 = t, c1 = t + 256;
    float acc[16][2];
#pragma unroll
    for (int r = 0; r < 16; ++r) { acc[r][0] = o1b[c0]; acc[r][1] = o1b[c1]; }
    for (int i = 0; i < 512; ++i) {
        float w0 = o1w[(long)i * 512 + c0], w1 = o1w[(long)i * 512 + c1];
#pragma unroll
        for (int r = 0; r < 16; ++r) {
            float h = hs[r * 512 + i];
            acc[r][0] += h * w0;
            acc[r][1] += h * w1;
        }
    }
    __syncthreads();
#pragma unroll
    for (int r = 0; r < 16; ++r) {
        hs[r * 512 + c0] = fmaxf(acc[r][0], 0.f);
        hs[r * 512 + c1] = fmaxf(acc[r][1], 0.f);
    }
    __syncthreads();

    float acc2[16];
#pragma unroll
    for (int r = 0; r < 16; ++r) acc2[r] = o2b[t];
    for (int i = 0; i < 512; ++i) {
        float w = o2w[(long)i * 256 + t];
#pragma unroll
        for (int r = 0; r < 16; ++r) acc2[r] += hs[r * 512 + i] * w;
    }
    __syncthreads();
#pragma unroll
    for (int r = 0; r < 16; ++r) hs[r * 256 + t] = acc2[r];
    __syncthreads();

    int wave = t >> 6, lane = t & 63;
    for (int rr = 0; rr < 4; ++rr) {
        int r = wave * 4 + rr;
        float v0 = hs[r * 256 + lane];
        float v1 = hs[r * 256 + 64 + lane];
        float v2 = hs[r * 256 + 128 + lane];
        float v3 = hs[r * 256 + 192 + lane];
        float m = fmaxf(fmaxf(v0, v1), fmaxf(v2, v3));
        for (int off = 32; off; off >>= 1) m = fmaxf(m, __shfl_xor(m, off));
        float s = __expf(v0 - m) + __expf(v1 - m) + __expf(v2 - m) + __expf(v3 - m);
        for (int off = 32; off; off >>= 1) s += __shfl_xor(s, off);
        float ls = m + logf(s);
        long ob = (row0 + r) * 256;
        out[ob + lane] = v0 - ls;
        out[ob + 64 + lane] = v1 - ls;
        out[ob + 128 + lane] = v2 - ls;
        out[ob + 192 + lane] = v3 - ls;
    }
}

extern "C" void kernel_launch(void* const* d_in, const int* in_sizes, int n_in,
                              void* d_out, int out_size, void* d_ws, size_t ws_size,
                              hipStream_t stream) {
    const int* x = (const int*)d_in[0];
    const float* mel = (const float*)d_in[1];
    const float* embed_w = (const float*)d_in[2];
    const float* conv_in_w = (const float*)d_in[3];
    const float* conv_in_b = (const float*)d_in[4];
    const float* conv_d1_w = (const float*)d_in[5];
    const float* conv_d1_b = (const float*)d_in[6];
    const float* conv_d2_w = (const float*)d_in[7];
    const float* conv_d2_b = (const float*)d_in[8];
    const float* up1_w = (const float*)d_in[9];
    const float* up1_b = (const float*)d_in[10];
    const float* up2_w = (const float*)d_in[11];
    const float* up2_b = (const float*)d_in[12];
    const float* up3_w = (const float*)d_in[13];
    const float* up3_b = (const float*)d_in[14];
    const float* bn_in_s = (const float*)d_in[15];
    const float* bn_in_o = (const float*)d_in[16];
    const float* bn_d1_s = (const float*)d_in[17];
    const float* bn_d1_o = (const float*)d_in[18];
    const float* bn_d2_s = (const float*)d_in[19];
    const float* bn_d2_o = (const float*)d_in[20];
    const float* bn_u1_s = (const float*)d_in[21];
    const float* bn_u1_o = (const float*)d_in[22];
    const float* bn_u2_s = (const float*)d_in[23];
    const float* bn_u2_o = (const float*)d_in[24];
    const float* bn_u3_s = (const float*)d_in[25];
    const float* bn_u3_o = (const float*)d_in[26];
    const float* gru_wi = (const float*)d_in[27];
    const float* gru_wh = (const float*)d_in[28];
    const float* gru_b = (const float*)d_in[29];
    const float* o1_w = (const float*)d_in[30];
    const float* o1_b = (const float*)d_in[31];
    const float* o2_w = (const float*)d_in[32];
    const float* o2_b = (const float*)d_in[33];

    float* ws = (float*)d_ws;
    float* out = (float*)d_out;

    unsigned long long* sDH = (unsigned long long*)(ws + OFF_SDH);
    unsigned long long* sDR = (unsigned long long*)(ws + OFF_SDR);
    float* mean = ws + OFF_MEAN;
    float* scale = ws + OFF_SCALE;
    float* offs = ws + OFF_OFFS;
    float* u0 = ws + OFF_U0;
    float* u0n = ws + OFF_U0N;
    float* r1 = ws + OFF_R1;
    float* u1 = ws + OFF_U1;
    float* r2 = ws + OFF_R2;
    float* u2 = ws + OFF_U2;
    float* y1 = ws + OFF_Y1;
    float* v1 = ws + OFF_V1;
    float* y2 = ws + OFF_Y2;
    float* v2 = ws + OFF_V2;
    float* y3 = ws + OFF_Y3;
    float* cond0 = ws + OFF_COND0;
    float* ewi = ws + OFF_EWI;
    float* cgx = ws + OFF_CGX;
    float* hseq = ws + OFF_HSEQ;

    init_kernel<<<16, 256, 0, stream>>>(ws);

    // conv_in (K3, rate1) + BN + relu
    conv1d_kernel<<<8 * 38, 512, 240 * 4, stream>>>(mel, conv_in_w, conv_in_b, u0, 40, 38, 80, 3, 1);
    bnstats_kernel<<<512, 64, 0, stream>>>(u0, bn_in_s, bn_in_o, mean, scale, offs, 304, 512);
    bnapply_kernel<<<155648 / 256, 256, 0, stream>>>(u0, u0n, mean, scale, offs, 155648);
    // dilated resblock 1
    conv1d_kernel<<<8 * 36, 512, 1024 * 4, stream>>>(u0n, conv_d1_w, conv_d1_b, r1, 38, 36, 512, 2, 2);
    bnstats_kernel<<<512, 64, 0, stream>>>(r1, bn_d1_s, bn_d1_o, mean, scale, offs, 288, 512);
    bnapply_add_kernel<<<147456 / 256, 256, 0, stream>>>(r1, u0n, u1, mean, scale, offs, 36, 38, 1);
    // dilated resblock 2
    conv1d_kernel<<<8 * 32, 512, 1024 * 4, stream>>>(u1, conv_d2_w, conv_d2_b, r2, 36, 32, 512, 2, 4);
    bnstats_kernel<<<512, 64, 0, stream>>>(r2, bn_d2_s, bn_d2_o, mean, scale, offs, 256, 512);
    bnapply_add_kernel<<<131072 / 256, 256, 0, stream>>>(r2, u1, u2, mean, scale, offs, 32, 36, 2);
    // upsample x2, x2, x4
    tconv1d_kernel<<<8 * 64, 512, 2048, stream>>>(u2, up1_w, up1_b, y1, 32, 2, 512);
    bnstats_kernel<<<512, 64, 0, stream>>>(y1, bn_u1_s, bn_u1_o, mean, scale, offs, 512, 512);
    bnapply_kernel<<<262144 / 256, 256, 0, stream>>>(y1, v1, mean, scale, offs, 262144);
    tconv1d_kernel<<<8 * 128, 512, 2048, stream>>>(v1, up2_w, up2_b, y2, 64, 2, 512);
    bnstats_kernel<<<512, 64, 0, stream>>>(y2, bn_u2_s, bn_u2_o, mean, scale, offs, 1024, 512);
    bnapply_kernel<<<524288 / 256, 256, 0, stream>>>(y2, v2, mean, scale, offs, 524288);
    tconv1d_kernel<<<8 * 512, 512, 2048, stream>>>(v2, up3_w, up3_b, y3, 128, 4, 512);
    bnstats_kernel<<<512, 64, 0, stream>>>(y3, bn_u3_s, bn_u3_o, mean, scale, offs, 4096, 512);
    bnapply_kernel<<<2097152 / 256, 256, 0, stream>>>(y3, cond0, mean, scale, offs, 2097152);

    // collapsed gx: ewi = embed@wi (256x1536), cgx = cond0@wi (4096x1536)
    rowgemm_kernel<<<16, 256, 0, stream>>>(embed_w, gru_wi, ewi, 256);
    rowgemm_kernel<<<256, 256, 0, stream>>>(cond0, gru_wi, cgx, 4096);

    // persistent GRU: 256 wgs x 512 threads; 84KB dynamic pad pins 1 WG/CU
    hipFuncSetAttribute(reinterpret_cast<const void*>(gru_kernel),
                        hipFuncAttributeMaxDynamicSharedMemorySize,
                        GRU_LDS_BYTES);
    gru_kernel<<<256, 512, GRU_LDS_BYTES, stream>>>(
        gru_wh, gru_b, x, ewi, cgx, sDH, sDR, hseq);

    // fused output head + log_softmax
    head_kernel<<<4096, 256, 0, stream>>>(hseq, o1_w, o1_b, o2_w, o2_b, out);
}